// Round 10
// baseline (218.475 us; speedup 1.0000x reference)
//
#include <hip/hip_runtime.h>
#include <math.h>
#include <stdint.h>

#define K_DIM 8192     // S*DIM
#define D_DIM 2048
#define M_ROWS 8192
#define N_W 32         // W columns (only 24 used in H)
#define NC 24
#define KSPLIT 8
#define KRANGE (K_DIM / KSPLIT)   // 1024 k per block
#define RPB 64                    // rows per block (4 waves x own 16 rows)
#define THREADS 256
#define CHUNKK 64                 // k per staged chunk
#define NCHUNK (KRANGE / CHUNKK)  // 16
#define PADF 68                   // padded LDS row stride (floats)

typedef short bf16x8 __attribute__((ext_vector_type(8)));
typedef float f32x4 __attribute__((ext_vector_type(4)));
union U32x4 { uint32_t u[4]; bf16x8 v; };

// wfrag (u16): [ks(256)][tile(2)][hilo(2)][lane(64)][e(8)] -> 1 MB total.
// Fragment (ks,tile,hilo) = contiguous 1KB; lane l reads 16B at l*16 ->
// coalesced wave read; L2-resident for all blocks.
#define WFRAG_IDX(ks, tile, hilo) ((((ks) * 2 + (tile)) * 2 + (hilo)) * 64)

// ---------------------------------------------------------------------------
// Kernel 0: prepack W -> bf16 hi/lo B-fragments (once); zero Hsum.
// k-map matches A-frag map: lane=((k&31)>>3)*16+(n&15), e=k&7 (same perm both
// sides of the MFMA so it cancels; only C/D layout matters).
// ---------------------------------------------------------------------------
__global__ __launch_bounds__(256) void mhc_prepack_kernel(
    const float* __restrict__ W, unsigned short* __restrict__ wfrag,
    float* __restrict__ Hsum)
{
    const int idx = blockIdx.x * 256 + threadIdx.x;   // 0 .. 262143
    const int k = idx >> 5, n = idx & 31;
    const float w = W[(size_t)k * N_W + n];
    const uint32_t u = __float_as_uint(w);
    const float hif = __uint_as_float(u & 0xFFFF0000u);
    const uint32_t ur = __float_as_uint(w - hif);

    const int ks = k >> 5, kk = k & 31;
    const int lane = ((kk >> 3) << 4) | (n & 15);
    const int e = kk & 7;
    const int tile = n >> 4;
    unsigned short* p = wfrag + ((size_t)WFRAG_IDX(ks, tile, 0) + lane) * 8 + e;
    p[0]   = (unsigned short)(u >> 16);    // hi  (hilo stride = 512 u16)
    p[512] = (unsigned short)(ur >> 16);   // lo

    if (idx < M_ROWS * NC) Hsum[idx] = 0.f;
}

// ---------------------------------------------------------------------------
// Kernel 1: partial H via MFMA, bf16 hi/lo split. H = Xhi@Whi+Xlo@Whi+Xhi@Wlo.
// Block = 256 thr (4 waves), 64 rows, 1024-k slice (blockIdx.y of 8).
// X is COALESCED-staged through a 64x64 LDS chunk (16 consecutive lanes read
// 256B contiguous of one row), padded stride 68 (2-way banks = free),
// double-buffered, reg-prefetched, ONE barrier per chunk. Wave wv owns rows
// [wv*16, wv*16+16): per kstep 2x ds_read_b128 (A), 4x 16B wfrag L2 loads
// (B), 6 MFMA. 4 blocks/CU (35KB LDS) = 16 waves/CU hides HBM + L2 latency.
// fp32 atomicAdd combine. C/D: D[row=(l>>4)*4+reg][col=l&15]  [HW-verified].
// ---------------------------------------------------------------------------
__global__ __launch_bounds__(THREADS, 4) void mhc_gemm_kernel(
    const float* __restrict__ X, const unsigned short* __restrict__ wfrag,
    float* __restrict__ Hsum)
{
    __shared__ __align__(16) float Xl[2][RPB * PADF];   // 2 x 17,408 B
    const int t = threadIdx.x;
    const int l = t & 63;
    const int wv = t >> 6;
    const int rowbase = blockIdx.x * RPB;
    const int kbase = blockIdx.y * KRANGE;

    f32x4 c0 = {0.f, 0.f, 0.f, 0.f};
    f32x4 c1 = {0.f, 0.f, 0.f, 0.f};
    const float4* __restrict__ Xg = reinterpret_cast<const float4*>(X);
    const bf16x8* __restrict__ wf = reinterpret_cast<const bf16x8*>(wfrag);

    float4 pf[4];
    auto LOADREGS = [&](int c) {
#pragma unroll
        for (int q = 0; q < 4; ++q) {
            const int F = q * THREADS + t;        // float4 idx in 64x16 chunk
            const int row = F >> 4, slot = F & 15;
            pf[q] = Xg[(size_t)(rowbase + row) * (K_DIM / 4)
                       + ((kbase + c * CHUNKK) >> 2) + slot];
        }
    };
    auto WRITELDS = [&](int b) {
#pragma unroll
        for (int q = 0; q < 4; ++q) {
            const int F = q * THREADS + t;
            const int row = F >> 4, slot = F & 15;
            *reinterpret_cast<float4*>(&Xl[b][row * PADF + slot * 4]) = pf[q];
        }
    };

    LOADREGS(0);
    WRITELDS(0);
    __syncthreads();

    for (int c = 0; c < NCHUNK; ++c) {
        if (c + 1 < NCHUNK) LOADREGS(c + 1);

        const float* xt = &Xl[c & 1][(wv * 16 + (l & 15)) * PADF + ((l >> 4) << 3)];
#pragma unroll
        for (int ksl = 0; ksl < 2; ++ksl) {
            const int ks = blockIdx.y * (KRANGE / 32) + c * 2 + ksl;
            const float4 xa = *reinterpret_cast<const float4*>(xt + ksl * 32);
            const float4 xb = *reinterpret_cast<const float4*>(xt + ksl * 32 + 4);
            float xs[8];
            xs[0] = xa.x; xs[1] = xa.y; xs[2] = xa.z; xs[3] = xa.w;
            xs[4] = xb.x; xs[5] = xb.y; xs[6] = xb.z; xs[7] = xb.w;

            U32x4 ah, al;
#pragma unroll
            for (int p = 0; p < 4; ++p) {
                const uint32_t u0 = __float_as_uint(xs[2 * p]);
                const uint32_t u1 = __float_as_uint(xs[2 * p + 1]);
                const float h0 = __uint_as_float(u0 & 0xFFFF0000u);
                const float h1 = __uint_as_float(u1 & 0xFFFF0000u);
                const uint32_t r0 = __float_as_uint(xs[2 * p] - h0);
                const uint32_t r1 = __float_as_uint(xs[2 * p + 1] - h1);
                ah.u[p] = (u1 & 0xFFFF0000u) | (u0 >> 16);
                al.u[p] = (r1 & 0xFFFF0000u) | (r0 >> 16);
            }

            const bf16x8 bh0 = wf[WFRAG_IDX(ks, 0, 0) + l];
            const bf16x8 bl0 = wf[WFRAG_IDX(ks, 0, 1) + l];
            const bf16x8 bh1 = wf[WFRAG_IDX(ks, 1, 0) + l];
            const bf16x8 bl1 = wf[WFRAG_IDX(ks, 1, 1) + l];

            c0 = __builtin_amdgcn_mfma_f32_16x16x32_bf16(ah.v, bh0, c0, 0, 0, 0);
            c0 = __builtin_amdgcn_mfma_f32_16x16x32_bf16(al.v, bh0, c0, 0, 0, 0);
            c0 = __builtin_amdgcn_mfma_f32_16x16x32_bf16(ah.v, bl0, c0, 0, 0, 0);
            c1 = __builtin_amdgcn_mfma_f32_16x16x32_bf16(ah.v, bh1, c1, 0, 0, 0);
            c1 = __builtin_amdgcn_mfma_f32_16x16x32_bf16(al.v, bh1, c1, 0, 0, 0);
            c1 = __builtin_amdgcn_mfma_f32_16x16x32_bf16(ah.v, bl1, c1, 0, 0, 0);
        }

        if (c + 1 < NCHUNK) {
            WRITELDS((c + 1) & 1);
            __syncthreads();
        }
    }

    // ---- combine: D[row=(l>>4)*4+r][col=l&15] ----
    const int drow = rowbase + wv * 16 + ((l >> 4) << 2);
    const int col = l & 15;
#pragma unroll
    for (int r = 0; r < 4; ++r)
        atomicAdd(&Hsum[(size_t)(drow + r) * NC + col], c0[r]);
    if (col < 8) {
#pragma unroll
        for (int r = 0; r < 4; ++r)
            atomicAdd(&Hsum[(size_t)(drow + r) * NC + 16 + col], c1[r]);
    }
}

// ---------------------------------------------------------------------------
// Kernel 2: params (transform + sinkhorn) + apply. One block per row.
// ---------------------------------------------------------------------------
__global__ __launch_bounds__(256) void mhc_apply_kernel(
    const float* __restrict__ X, const float* __restrict__ Hsum,
    const float* __restrict__ ab, float* __restrict__ out)
{
    __shared__ float pbuf[NC];
    const int row = blockIdx.x;
    const int t = threadIdx.x;

    if (t < 64) {
        const int lane = t;
        const float pl = (lane < NC) ? Hsum[(size_t)row * NC + lane] : 0.f;
        const float bias  = (lane < NC) ? ab[lane] : 0.f;
        const float scale = ab[(lane < 16) ? 24 : ((lane < 20) ? 25 : 26)];

        float vout;
        if (lane < 16) {
            vout = __expf(fmaf(scale, pl, bias));                 // exp(a_res*H+b)
        } else {
            vout = fmaf(scale, 1.f / (1.f + __expf(-pl)), bias);  // a*sigmoid(H)+b
        }

        // Sinkhorn on lanes 0..15: lane = s*4 + i.
        float p = vout;
        for (int it = 0; it < 20; ++it) {
            float rs = p + __shfl_xor(p, 1);
            rs += __shfl_xor(rs, 2);
            p = p / rs;
            float cs = p + __shfl_xor(p, 4);
            cs += __shfl_xor(cs, 8);
            p = p / cs;
        }
        if (lane < NC) pbuf[lane] = (lane < 16) ? p : vout;
    }
    __syncthreads();

    float hres[4][4], hpre[4], hpos[4];
#pragma unroll
    for (int i = 0; i < 16; ++i) hres[i >> 2][i & 3] = pbuf[i];
#pragma unroll
    for (int i = 0; i < 4; ++i) hpre[i] = pbuf[16 + i];
#pragma unroll
    for (int i = 0; i < 4; ++i) hpos[i] = pbuf[20 + i];

    const float4* __restrict__ Xr =
        reinterpret_cast<const float4*>(X + (size_t)row * K_DIM);
    float4* __restrict__ Or = reinterpret_cast<float4*>(out + (size_t)row * K_DIM);

#pragma unroll
    for (int q = 0; q < 2; ++q) {
        const int pos = t + q * 256;          // float4 index within a 2048-seg
        float4 xq[4];
#pragma unroll
        for (int i = 0; i < 4; ++i) xq[i] = Xr[i * (D_DIM / 4) + pos];

        float y[4];
#pragma unroll
        for (int e = 0; e < 4; ++e) {
            float s = 0.f;
#pragma unroll
            for (int i = 0; i < 4; ++i)
                s = fmaf(hpre[i], reinterpret_cast<const float*>(&xq[i])[e], s);
            y[e] = s;
        }

#pragma unroll
        for (int s = 0; s < 4; ++s) {
            float4 o;
            float* oe = reinterpret_cast<float*>(&o);
#pragma unroll
            for (int e = 0; e < 4; ++e) {
                float v = hpos[s] * y[e];
#pragma unroll
                for (int i = 0; i < 4; ++i)
                    v = fmaf(hres[s][i], reinterpret_cast<const float*>(&xq[i])[e], v);
                oe[e] = v;
            }
            Or[s * (D_DIM / 4) + pos] = o;
        }
    }
}

extern "C" void kernel_launch(void* const* d_in, const int* in_sizes, int n_in,
                              void* d_out, int out_size, void* d_ws, size_t ws_size,
                              hipStream_t stream) {
    const float* X  = (const float*)d_in[0];
    const float* W  = (const float*)d_in[1];
    const float* ab = (const float*)d_in[2];
    float* out = (float*)d_out;
    unsigned short* wfrag = (unsigned short*)d_ws;          // 1,048,576 B
    float* Hsum = (float*)((char*)d_ws + 1048576);          // + 786,432 B

    mhc_prepack_kernel<<<(K_DIM * N_W) / 256, 256, 0, stream>>>(W, wfrag, Hsum);
    dim3 g1(M_ROWS / RPB, KSPLIT);
    mhc_gemm_kernel<<<g1, THREADS, 0, stream>>>(X, wfrag, Hsum);
    mhc_apply_kernel<<<M_ROWS, 256, 0, stream>>>(X, Hsum, ab, out);
}

// Round 11
// 172.253 us; speedup vs baseline: 1.2683x; 1.2683x over previous
//
#include <hip/hip_runtime.h>
#include <math.h>
#include <stdint.h>

#define K_DIM 8192     // S*DIM
#define D_DIM 2048
#define M_ROWS 8192
#define N_W 32         // W columns (only 24 used in H)
#define NC 24
#define KSPLIT 16
#define KRANGE 512                // k per block
#define KSB 16                    // ksteps (of 32) per block
#define RPB 16                    // rows per block = one MFMA tile
#define THR 512                   // 8 waves; wave kq owns ksteps {2kq,2kq+1}
#define PADF 516                  // padded LDS X row stride (floats)

typedef short bf16x8 __attribute__((ext_vector_type(8)));
typedef float f32x4 __attribute__((ext_vector_type(4)));
union U32x4 { uint32_t u[4]; bf16x8 v; };

// wfrag (u16, W hi-only rne-rounded): [ks(256)][tile(2)][lane(64)][e(8)]
// -> 512 KB total; a block's 16-kstep slice = 32 KB contiguous.
#define WFRAG_IDX(ks, tile) (((ks) * 2 + (tile)) * 64)

// ---------------------------------------------------------------------------
// Kernel 0: prepack W -> rne-rounded bf16 B-fragments (once); zero Hsum.
// k-map matches A-frag map: lane=((k&31)>>3)*16+(n&15), e=k&7 (same perm on
// both MFMA operands so it cancels; only C/D layout matters).
// ---------------------------------------------------------------------------
__global__ __launch_bounds__(256) void mhc_prepack_kernel(
    const float* __restrict__ W, unsigned short* __restrict__ wfrag,
    float* __restrict__ Hsum)
{
    const int idx = blockIdx.x * 256 + threadIdx.x;   // 0 .. 262143
    const int k = idx >> 5, n = idx & 31;
    const float w = W[(size_t)k * N_W + n];
    const uint32_t u = __float_as_uint(w);
    const uint32_t r = u + 0x7FFFu + ((u >> 16) & 1u);   // round-to-nearest-even

    const int ks = k >> 5, kk = k & 31;
    const int lane = ((kk >> 3) << 4) | (n & 15);
    const int e = kk & 7;
    const int tile = n >> 4;
    wfrag[((size_t)WFRAG_IDX(ks, tile) + lane) * 8 + e] = (unsigned short)(r >> 16);

    if (idx < M_ROWS * NC) Hsum[idx] = 0.f;
}

// ---------------------------------------------------------------------------
// Kernel 1: partial H via MFMA, H = Xhi@W + Xlo@W (W rne-bf16; X exact split).
// Apply-kernel-shaped: 8192 short-lived blocks (grid 512 x 16), 512 thr.
// Block = 16 rows x 512 k. Stage once, 2 barriers total:
//   - X: each wave reads 2 rows as 2KB CONTIGUOUS runs (1KB per instr) ->
//     LDS [16][516] padded (writes conflict-free; A-frag b128 reads 2-way=free)
//   - B: 32KB prepacked slice copied LDS-linear (coalesced)
// Wave kq computes ksteps {2kq, 2kq+1}: 4x ds_read_b128 (A), 4x b128 (B),
// ~50 VALU pack, 4 MFMA. LDS-reduce 8 partials; one atomicAdd per (row,col).
// C/D: D[row=(l>>4)*4+reg][col=l&15]  [HW-verified].
// ---------------------------------------------------------------------------
__global__ __launch_bounds__(THR, 4) void mhc_gemm_kernel(
    const float* __restrict__ X, const unsigned short* __restrict__ wfrag,
    float* __restrict__ Hsum)
{
    __shared__ __align__(16) float Xl[RPB * PADF];              // 33,024 B
    __shared__ __align__(16) unsigned short bfr[KSB * 2 * 64 * 8]; // 32,768 B
    __shared__ float Hpart[8][RPB][NC];                          // 12,288 B

    const int t = threadIdx.x;
    const int l = t & 63;
    const int wv = t >> 6;
    const int rowbase = blockIdx.x * RPB;
    const int kb4 = blockIdx.y * (KRANGE / 4);    // float4 col base

    const float4* __restrict__ Xg = reinterpret_cast<const float4*>(X);

    // ---- stage X: wave wv owns rows {2wv, 2wv+1}; 2x 1KB runs per row ----
    float4 pf[4];
#pragma unroll
    for (int j = 0; j < 4; ++j)
        pf[j] = Xg[(size_t)(rowbase + wv * 2 + (j >> 1)) * (K_DIM / 4)
                   + kb4 + (j & 1) * 64 + l];

    // ---- stage B slice: 32KB contiguous, coalesced, LDS-linear ----
    {
        const float4* __restrict__ bsrc = reinterpret_cast<const float4*>(
            wfrag + (size_t)blockIdx.y * (KSB * 2 * 64 * 8));
        float4* bdst = reinterpret_cast<float4*>(bfr);
#pragma unroll
        for (int i = 0; i < 4; ++i)
            bdst[i * THR + t] = bsrc[i * THR + t];
    }

#pragma unroll
    for (int j = 0; j < 4; ++j)
        *reinterpret_cast<float4*>(
            &Xl[(wv * 2 + (j >> 1)) * PADF + ((j & 1) * 64 + l) * 4]) = pf[j];
    __syncthreads();

    // ---- compute: wave kq = wv does ksteps {2kq, 2kq+1} ----
    f32x4 c0 = {0.f, 0.f, 0.f, 0.f};
    f32x4 c1 = {0.f, 0.f, 0.f, 0.f};
    const bf16x8* __restrict__ bf = reinterpret_cast<const bf16x8*>(bfr);
    const float* xbase = &Xl[(l & 15) * PADF + ((l >> 4) << 3)];

#pragma unroll
    for (int u = 0; u < 2; ++u) {
        const int ksl = wv * 2 + u;               // kstep within block (0..15)
        const float4 xa = *reinterpret_cast<const float4*>(xbase + ksl * 32);
        const float4 xb = *reinterpret_cast<const float4*>(xbase + ksl * 32 + 4);
        float xs[8];
        xs[0] = xa.x; xs[1] = xa.y; xs[2] = xa.z; xs[3] = xa.w;
        xs[4] = xb.x; xs[5] = xb.y; xs[6] = xb.z; xs[7] = xb.w;

        U32x4 ah, al;
#pragma unroll
        for (int p = 0; p < 4; ++p) {
            const uint32_t u0 = __float_as_uint(xs[2 * p]);
            const uint32_t u1 = __float_as_uint(xs[2 * p + 1]);
            const float h0 = __uint_as_float(u0 & 0xFFFF0000u);
            const float h1 = __uint_as_float(u1 & 0xFFFF0000u);
            const uint32_t r0 = __float_as_uint(xs[2 * p] - h0);
            const uint32_t r1 = __float_as_uint(xs[2 * p + 1] - h1);
            ah.u[p] = (u1 & 0xFFFF0000u) | (u0 >> 16);
            al.u[p] = (r1 & 0xFFFF0000u) | (r0 >> 16);
        }

        const bf16x8 bh0 = bf[WFRAG_IDX(ksl, 0) + l];
        const bf16x8 bh1 = bf[WFRAG_IDX(ksl, 1) + l];

        c0 = __builtin_amdgcn_mfma_f32_16x16x32_bf16(ah.v, bh0, c0, 0, 0, 0);
        c0 = __builtin_amdgcn_mfma_f32_16x16x32_bf16(al.v, bh0, c0, 0, 0, 0);
        c1 = __builtin_amdgcn_mfma_f32_16x16x32_bf16(ah.v, bh1, c1, 0, 0, 0);
        c1 = __builtin_amdgcn_mfma_f32_16x16x32_bf16(al.v, bh1, c1, 0, 0, 0);
    }

    // ---- stash partials: D[row=(l>>4)*4+r][col=l&15] ----
#pragma unroll
    for (int r = 0; r < 4; ++r)
        Hpart[wv][((l >> 4) << 2) + r][l & 15] = c0[r];
    if ((l & 15) < 8) {
#pragma unroll
        for (int r = 0; r < 4; ++r)
            Hpart[wv][((l >> 4) << 2) + r][16 + (l & 15)] = c1[r];
    }
    __syncthreads();

    if (t < RPB * NC) {
        const int row = t / NC, col = t % NC;
        float h = 0.f;
#pragma unroll
        for (int w = 0; w < 8; ++w) h += Hpart[w][row][col];
        atomicAdd(&Hsum[(size_t)(rowbase + row) * NC + col], h);
    }
}

// ---------------------------------------------------------------------------
// Kernel 2: params (transform + sinkhorn) + apply. One block per row.
// ---------------------------------------------------------------------------
__global__ __launch_bounds__(256) void mhc_apply_kernel(
    const float* __restrict__ X, const float* __restrict__ Hsum,
    const float* __restrict__ ab, float* __restrict__ out)
{
    __shared__ float pbuf[NC];
    const int row = blockIdx.x;
    const int t = threadIdx.x;

    if (t < 64) {
        const int lane = t;
        const float pl = (lane < NC) ? Hsum[(size_t)row * NC + lane] : 0.f;
        const float bias  = (lane < NC) ? ab[lane] : 0.f;
        const float scale = ab[(lane < 16) ? 24 : ((lane < 20) ? 25 : 26)];

        float vout;
        if (lane < 16) {
            vout = __expf(fmaf(scale, pl, bias));                 // exp(a_res*H+b)
        } else {
            vout = fmaf(scale, 1.f / (1.f + __expf(-pl)), bias);  // a*sigmoid(H)+b
        }

        // Sinkhorn on lanes 0..15: lane = s*4 + i.
        float p = vout;
        for (int it = 0; it < 20; ++it) {
            float rs = p + __shfl_xor(p, 1);
            rs += __shfl_xor(rs, 2);
            p = p / rs;
            float cs = p + __shfl_xor(p, 4);
            cs += __shfl_xor(cs, 8);
            p = p / cs;
        }
        if (lane < NC) pbuf[lane] = (lane < 16) ? p : vout;
    }
    __syncthreads();

    float hres[4][4], hpre[4], hpos[4];
#pragma unroll
    for (int i = 0; i < 16; ++i) hres[i >> 2][i & 3] = pbuf[i];
#pragma unroll
    for (int i = 0; i < 4; ++i) hpre[i] = pbuf[16 + i];
#pragma unroll
    for (int i = 0; i < 4; ++i) hpos[i] = pbuf[20 + i];

    const float4* __restrict__ Xr =
        reinterpret_cast<const float4*>(X + (size_t)row * K_DIM);
    float4* __restrict__ Or = reinterpret_cast<float4*>(out + (size_t)row * K_DIM);

#pragma unroll
    for (int q = 0; q < 2; ++q) {
        const int pos = t + q * 256;          // float4 index within a 2048-seg
        float4 xq[4];
#pragma unroll
        for (int i = 0; i < 4; ++i) xq[i] = Xr[i * (D_DIM / 4) + pos];

        float y[4];
#pragma unroll
        for (int e = 0; e < 4; ++e) {
            float s = 0.f;
#pragma unroll
            for (int i = 0; i < 4; ++i)
                s = fmaf(hpre[i], reinterpret_cast<const float*>(&xq[i])[e], s);
            y[e] = s;
        }

#pragma unroll
        for (int s = 0; s < 4; ++s) {
            float4 o;
            float* oe = reinterpret_cast<float*>(&o);
#pragma unroll
            for (int e = 0; e < 4; ++e) {
                float v = hpos[s] * y[e];
#pragma unroll
                for (int i = 0; i < 4; ++i)
                    v = fmaf(hres[s][i], reinterpret_cast<const float*>(&xq[i])[e], v);
                oe[e] = v;
            }
            Or[s * (D_DIM / 4) + pos] = o;
        }
    }
}

extern "C" void kernel_launch(void* const* d_in, const int* in_sizes, int n_in,
                              void* d_out, int out_size, void* d_ws, size_t ws_size,
                              hipStream_t stream) {
    const float* X  = (const float*)d_in[0];
    const float* W  = (const float*)d_in[1];
    const float* ab = (const float*)d_in[2];
    float* out = (float*)d_out;
    unsigned short* wfrag = (unsigned short*)d_ws;          // 524,288 B
    float* Hsum = (float*)((char*)d_ws + 524288);           // + 786,432 B

    mhc_prepack_kernel<<<(K_DIM * N_W) / 256, 256, 0, stream>>>(W, wfrag, Hsum);
    dim3 g1(M_ROWS / RPB, KSPLIT);
    mhc_gemm_kernel<<<g1, THR, 0, stream>>>(X, wfrag, Hsum);
    mhc_apply_kernel<<<M_ROWS, 256, 0, stream>>>(X, Hsum, ab, out);
}